// Round 13
// baseline (336.518 us; speedup 1.0000x reference)
//
#include <hip/hip_runtime.h>
#include <hip/hip_bf16.h>

// GRU-like fused cell: out = (1-z)*tanh(i_n + r*h_n) + z*e
// B=8, H=512, N=8192. bf16 MFMA 16x16x32, fp32 acc, fused epilogue.
//
// R12 -> R13: R12 (conflicts 0, coalesced) sits at 6.5k cyc/slot vs ~3k pipe
// floor -- 2 waves/SIMD collide in identical phases (ds_read bursts, then MFMA
// bursts; each pipe idles half the slot). R9 proved 4 waves/SIMD fits regs
// (wave tile 32x32, acc 64, VGPR 64) but had anti-coalesced X. R13 combines:
// R9 frame (512thr, 8 waves, launch_bounds(512,4), 2 WGs/CU = 16 waves/CU)
// + R12's coalesced X loads + audited floor swizzles (verbatim formulas).

#define HH 512
#define NBATCH 8
#define NN 8192
#define BN 128
#define BK 64
#define NSTEPS 16
#define THREADS 512
#define A_BYTES (192 * BK * 2)          // 24576
#define B_BYTES (BN * 128)              // 16384
#define BUF_BYTES (A_BYTES + B_BYTES)   // 40960
#define LDS_TOTAL (2 * BUF_BYTES)       // 81920 -> 2 WGs/CU (163840 = full LDS)

typedef __attribute__((ext_vector_type(8))) short short8;
typedef __attribute__((ext_vector_type(4))) float f32x4;

__device__ __forceinline__ unsigned cvt_pk_bf16(float a, float b) {
  unsigned r;
  asm("v_cvt_pk_bf16_f32 %0, %1, %2" : "=v"(r) : "v"(a), "v"(b));
  return r;
}

__device__ __forceinline__ void gload_lds16(const void* g, void* l) {
  __builtin_amdgcn_global_load_lds(
      (__attribute__((address_space(1))) void*)(g),
      (__attribute__((address_space(3))) void*)(l), 16, 0, 0);
}

#define MFMA16(a_, b_, c_) __builtin_amdgcn_mfma_f32_16x16x32_bf16((a_), (b_), (c_), 0, 0, 0)

// ---------------- weight pre-pack (unchanged, verified R1-R12) ----------------
__global__ void prepack_w(const float* __restrict__ W_ih, const float* __restrict__ W_hh,
                          __hip_bfloat16* __restrict__ ws) {
  int t = blockIdx.x * 256 + threadIdx.x;
  int blk = t / 12288;                              // ht*16 + s
  int e = t % 12288;
  int ra = e >> 6;                                  // 0..191
  int kk = (e & 63) ^ ((ra & 7) << 3);              // inverse of read-side XOR swizzle
  int gate = ra >> 6;
  int h = (blk >> 4) * 64 + (ra & 63);
  int row = gate * HH + h;
  int kg = (blk & 15) * 64 + kk;
  float v = (kg < 512) ? W_ih[row * 512 + kg] : W_hh[row * 512 + (kg - 512)];
  ws[t] = __float2bfloat16(v);
}

// ---------------- main fused kernel ----------------
__global__ __launch_bounds__(THREADS, 4)   // 128-reg cap (64 VGPR + acc in AGPR)
void gru_main(const float* __restrict__ e_wv, const float* __restrict__ m_wv,
              const __hip_bfloat16* __restrict__ wimg, float* __restrict__ out) {
  extern __shared__ char smem[];
  const int tid  = threadIdx.x;
  const int lane = tid & 63;
  const int wave = tid >> 6;       // 0..7
  const int wm = wave >> 2;        // 0..1 : 32-row half of 64-h tile
  const int wn = wave & 3;         // 0..3 : 32-col quarter of 128-n tile

  // XCD swizzle (bijective: 4096 % 8 == 0), ht fastest.
  const int wg  = blockIdx.x;
  const int swz = (wg & 7) * 512 + (wg >> 3);
  const int ht  = swz & 7;
  const int nt  = (swz >> 3) & 63;
  const int b   = swz >> 9;

  const size_t batch_off = (size_t)b * HH * NN;
  // Coalesced X: wave w owns k-rows [8w, 8w+8); per row 64 lanes x float2 = 512B.
  const float* xm = m_wv + batch_off + (size_t)(8 * wave) * NN + nt * BN + 2 * lane;
  const float* xe = e_wv + batch_off + (size_t)(8 * wave) * NN + nt * BN + 2 * lane;
  const char*  wA = (const char*)wimg + (size_t)ht * NSTEPS * A_BYTES + tid * 16;

  f32x4 acc_r[2][2]  = {};
  f32x4 acc_z[2][2]  = {};
  f32x4 acc_in[2][2] = {};
  f32x4 acc_hn[2][2] = {};
  float2 xR[8];   // transient staged X (16 VGPRs)

  // Read offsets: A (R1-R12 verified, 0 conflicts), B (R12 floor swizzle, 0 conflicts).
  int aoff[2], boff[2];
#pragma unroll
  for (int kb2 = 0; kb2 < 2; ++kb2) {
    const int K = kb2 * 64 + ((lane >> 4) << 4);
    aoff[kb2] = (wm * 32 + (lane & 15)) * 128 + (K ^ ((lane & 7) << 4));
    boff[kb2] = A_BYTES + (wn * 32 + (lane & 15)) * 128
              + (K ^ (((lane >> 1) & 7) << 4));
  }

  auto issue_A = [&](int s, char* nb) {
    const char* gA = wA + (size_t)s * A_BYTES;
    char* lA = nb + tid * 16;
#pragma unroll
    for (int i = 0; i < 3; ++i)
      gload_lds16(gA + i * 8192, lA + i * 8192);
  };
  auto x_load = [&](const float* xs) {
#pragma unroll
    for (int i = 0; i < 8; ++i)
      xR[i] = *(const float2*)(xs + (size_t)i * NN);
  };
  auto write_X = [&](char* nb) {
    // rows 2*lane, 2*lane+1; k-octet b128; stored byte = K ^ (((row>>1)&7)<<4)
    char* Bb = nb + A_BYTES + (2 * lane) * 128;
    const int kb = (16 * wave) ^ ((lane & 7) << 4);
    uint4 w0, w1;
    w0.x = cvt_pk_bf16(xR[0].x, xR[1].x);
    w0.y = cvt_pk_bf16(xR[2].x, xR[3].x);
    w0.z = cvt_pk_bf16(xR[4].x, xR[5].x);
    w0.w = cvt_pk_bf16(xR[6].x, xR[7].x);
    w1.x = cvt_pk_bf16(xR[0].y, xR[1].y);
    w1.y = cvt_pk_bf16(xR[2].y, xR[3].y);
    w1.z = cvt_pk_bf16(xR[4].y, xR[5].y);
    w1.w = cvt_pk_bf16(xR[6].y, xR[7].y);
    *(uint4*)(Bb + kb)       = w0;   // row 2*lane
    *(uint4*)(Bb + 128 + kb) = w1;   // row 2*lane+1
  };
  auto compute_kb2 = [&](const char* cb, int kb2, bool firstHalf) {
    short8 bfr[2];
#pragma unroll
    for (int ni = 0; ni < 2; ++ni)
      bfr[ni] = *(const short8*)(cb + boff[kb2] + ni * 2048);
    {  // gate r
      short8 a0 = *(const short8*)(cb + aoff[kb2]);
      short8 a1 = *(const short8*)(cb + aoff[kb2] + 2048);
#pragma unroll
      for (int ni = 0; ni < 2; ++ni) {
        acc_r[0][ni] = MFMA16(a0, bfr[ni], acc_r[0][ni]);
        acc_r[1][ni] = MFMA16(a1, bfr[ni], acc_r[1][ni]);
      }
    }
    {  // gate z
      short8 a0 = *(const short8*)(cb + aoff[kb2] + 8192);
      short8 a1 = *(const short8*)(cb + aoff[kb2] + 8192 + 2048);
#pragma unroll
      for (int ni = 0; ni < 2; ++ni) {
        acc_z[0][ni] = MFMA16(a0, bfr[ni], acc_z[0][ni]);
        acc_z[1][ni] = MFMA16(a1, bfr[ni], acc_z[1][ni]);
      }
    }
    {  // gate n -> acc_in (m-phase) / acc_hn (e-phase)
      short8 a0 = *(const short8*)(cb + aoff[kb2] + 16384);
      short8 a1 = *(const short8*)(cb + aoff[kb2] + 16384 + 2048);
      if (firstHalf) {
#pragma unroll
        for (int ni = 0; ni < 2; ++ni) {
          acc_in[0][ni] = MFMA16(a0, bfr[ni], acc_in[0][ni]);
          acc_in[1][ni] = MFMA16(a1, bfr[ni], acc_in[1][ni]);
        }
      } else {
#pragma unroll
        for (int ni = 0; ni < 2; ++ni) {
          acc_hn[0][ni] = MFMA16(a0, bfr[ni], acc_hn[0][ni]);
          acc_hn[1][ni] = MFMA16(a1, bfr[ni], acc_hn[1][ni]);
        }
      }
    }
  };

  // prologue: stage step 0 into buf0
  issue_A(0, smem);
  x_load(xm);
  write_X(smem);
  __syncthreads();

#pragma unroll 1
  for (int s = 0; s < NSTEPS; ++s) {
    char* cb = smem + ((s & 1) ? BUF_BYTES : 0);
    char* nb = smem + ((s & 1) ? 0 : BUF_BYTES);
    const bool pre = (s < NSTEPS - 1);
    const bool firstHalf = (s < 8);

    if (pre) {
      const int t = s + 1;
      x_load((t < 8 ? xm : xe) + (size_t)(t & 7) * (64 * NN));  // in flight over compute
      issue_A(t, nb);
    }
    __builtin_amdgcn_s_setprio(1);
    compute_kb2(cb, 0, firstHalf);
    compute_kb2(cb, 1, firstHalf);
    __builtin_amdgcn_s_setprio(0);
    if (pre) write_X(nb);
    __syncthreads();
  }

  // epilogue: gates + blend (same math, wave tile 32h x 32n)
  const size_t obase = batch_off + (size_t)(ht * 64 + wm * 32) * NN + nt * BN + wn * 32;
  const float* ep = e_wv + obase;
  float* op = out + obase;
  const int rsub = (lane >> 4) << 2;
  const int csub = lane & 15;
#pragma unroll
  for (int mi = 0; mi < 2; ++mi)
#pragma unroll
    for (int ni = 0; ni < 2; ++ni) {
#pragma unroll
      for (int r = 0; r < 4; ++r) {
        size_t idx = (size_t)(mi * 16 + rsub + r) * NN + ni * 16 + csub;
        float pr  = acc_r[mi][ni][r];
        float pz  = acc_z[mi][ni][r];
        float vin = acc_in[mi][ni][r];
        float vhn = acc_hn[mi][ni][r];
        float rr  = 1.f / (1.f + __expf(-pr));
        float zz  = 1.f / (1.f + __expf(-pz));
        float ex  = __expf(2.f * (vin + rr * vhn));
        float nn2 = 1.f - 2.f / (ex + 1.f);      // tanh, inf-safe
        float ev  = ep[idx];
        op[idx] = (1.f - zz) * nn2 + zz * ev;
      }
    }
}

extern "C" void kernel_launch(void* const* d_in, const int* in_sizes, int n_in,
                              void* d_out, int out_size, void* d_ws, size_t ws_size,
                              hipStream_t stream) {
  const float* e_wv = (const float*)d_in[0];
  const float* m_wv = (const float*)d_in[1];
  const float* W_ih = (const float*)d_in[2];
  const float* W_hh = (const float*)d_in[3];
  float* out = (float*)d_out;
  __hip_bfloat16* wimg = (__hip_bfloat16*)d_ws;   // 3 MiB weight image

  (void)hipFuncSetAttribute((const void*)gru_main,
                            hipFuncAttributeMaxDynamicSharedMemorySize, LDS_TOTAL);

  prepack_w<<<(NBATCH * NSTEPS * 12288) / 256, 256, 0, stream>>>(W_ih, W_hh, wimg);
  gru_main<<<NBATCH * 8 * 64, THREADS, LDS_TOTAL, stream>>>(e_wv, m_wv, wimg, out);
}

// Round 14
// 334.828 us; speedup vs baseline: 1.0050x; 1.0050x over previous
//
#include <hip/hip_runtime.h>
#include <hip/hip_bf16.h>

// GRU-like fused cell: out = (1-z)*tanh(i_n + r*h_n) + z*e
// B=8, H=512, N=8192. bf16 MFMA 16x16x32, fp32 acc, fused epilogue.
//
// R13 -> R14: wall at ~350us = the 2-phase structural ceiling (650 TF-equiv,
// matches m233/m248). R7's counted-vmcnt "failure" was masked by anti-coalesced
// X loads; retest on the clean R12 kernel. T4-correct schedule: every waited-on
// vm op is a full step old --
//   top:   issue_A(s+1) [oldest] -> write_X (waits vmcnt(6), step-old X(s+1))
//          -> x_load X(s+2) [flies a full step]
//   compute (setprio)
//   barrier: s_waitcnt vmcnt(16) lgkmcnt(0) + raw s_barrier
//            (A(s+1) guaranteed landed; X(s+2) stays in flight)
// No vmcnt(0) in steady state.

#define HH 512
#define NBATCH 8
#define NN 8192
#define BN 128
#define BK 64
#define NSTEPS 16
#define THREADS 256
#define A_BYTES (192 * BK * 2)          // 24576
#define B_BYTES (BN * 128)              // 16384
#define BUF_BYTES (A_BYTES + B_BYTES)   // 40960
#define LDS_TOTAL (2 * BUF_BYTES)       // 81920 -> 2 WGs/CU

typedef __attribute__((ext_vector_type(8))) short short8;
typedef __attribute__((ext_vector_type(4))) float f32x4;

__device__ __forceinline__ unsigned cvt_pk_bf16(float a, float b) {
  unsigned r;
  asm("v_cvt_pk_bf16_f32 %0, %1, %2" : "=v"(r) : "v"(a), "v"(b));
  return r;
}

__device__ __forceinline__ void gload_lds16(const void* g, void* l) {
  __builtin_amdgcn_global_load_lds(
      (__attribute__((address_space(1))) void*)(g),
      (__attribute__((address_space(3))) void*)(l), 16, 0, 0);
}

#define MFMA16(a_, b_, c_) __builtin_amdgcn_mfma_f32_16x16x32_bf16((a_), (b_), (c_), 0, 0, 0)

// ---------------- weight pre-pack (unchanged, verified R1-R13) ----------------
__global__ void prepack_w(const float* __restrict__ W_ih, const float* __restrict__ W_hh,
                          __hip_bfloat16* __restrict__ ws) {
  int t = blockIdx.x * 256 + threadIdx.x;
  int blk = t / 12288;                              // ht*16 + s
  int e = t % 12288;
  int ra = e >> 6;                                  // 0..191
  int kk = (e & 63) ^ ((ra & 7) << 3);              // inverse of read-side XOR swizzle
  int gate = ra >> 6;
  int h = (blk >> 4) * 64 + (ra & 63);
  int row = gate * HH + h;
  int kg = (blk & 15) * 64 + kk;
  float v = (kg < 512) ? W_ih[row * 512 + kg] : W_hh[row * 512 + (kg - 512)];
  ws[t] = __float2bfloat16(v);
}

// ---------------- main fused kernel ----------------
__global__ __launch_bounds__(THREADS, 2)
void gru_main(const float* __restrict__ e_wv, const float* __restrict__ m_wv,
              const __hip_bfloat16* __restrict__ wimg, float* __restrict__ out) {
  extern __shared__ char smem[];
  const int tid  = threadIdx.x;
  const int lane = tid & 63;
  const int wave = tid >> 6;       // 0..3
  const int wm = wave >> 1;        // 0..1 : 32-row half of 64-h tile
  const int wn = wave & 1;         // 0..1 : 64-col half of 128-n tile

  // XCD swizzle (bijective: 4096 % 8 == 0), ht fastest.
  const int wg  = blockIdx.x;
  const int swz = (wg & 7) * 512 + (wg >> 3);
  const int ht  = swz & 7;
  const int nt  = (swz >> 3) & 63;
  const int b   = swz >> 9;

  const size_t batch_off = (size_t)b * HH * NN;
  // Coalesced X: wave w owns k-rows [16w,16w+16); per row 64 lanes x float2.
  const float* xm = m_wv + batch_off + (size_t)(16 * wave) * NN + nt * BN + 2 * lane;
  const float* xe = e_wv + batch_off + (size_t)(16 * wave) * NN + nt * BN + 2 * lane;
  const char*  wA = (const char*)wimg + (size_t)ht * NSTEPS * A_BYTES + tid * 16;

  f32x4 acc_r[2][4]  = {};
  f32x4 acc_z[2][4]  = {};
  f32x4 acc_in[2][4] = {};
  f32x4 acc_hn[2][4] = {};
  float2 xR[16];   // staged X (32 VGPRs), lives across one barrier

  // Read offsets (R12-verified, 0 conflicts).
  int aoff[2], boff[2];
#pragma unroll
  for (int kb2 = 0; kb2 < 2; ++kb2) {
    const int K = kb2 * 64 + ((lane >> 4) << 4);
    aoff[kb2] = (wm * 32 + (lane & 15)) * 128 + (K ^ ((lane & 7) << 4));
    boff[kb2] = A_BYTES + (wn * 64 + (lane & 15)) * 128
              + (K ^ (((lane >> 1) & 7) << 4));
  }

  auto issue_A = [&](int s, char* nb) {
    const char* gA = wA + (size_t)s * A_BYTES;
    char* lA = nb + tid * 16;
#pragma unroll
    for (int i = 0; i < 6; ++i)
      gload_lds16(gA + i * 4096, lA + i * 4096);
  };
  auto x_load = [&](const float* xs) {
#pragma unroll
    for (int i = 0; i < 16; ++i)
      xR[i] = *(const float2*)(xs + (size_t)i * NN);
  };
  auto write_X = [&](char* nb) {
    // k-octet b128 writes: rows 2*lane, 2*lane+1; stored byte = K ^ ((lane&7)<<4)
    char* Bb = nb + A_BYTES + (2 * lane) * 128;
    const int sx = (lane & 7) << 4;
#pragma unroll
    for (int o = 0; o < 2; ++o) {
      uint4 w0, w1;
      w0.x = cvt_pk_bf16(xR[8 * o + 0].x, xR[8 * o + 1].x);
      w0.y = cvt_pk_bf16(xR[8 * o + 2].x, xR[8 * o + 3].x);
      w0.z = cvt_pk_bf16(xR[8 * o + 4].x, xR[8 * o + 5].x);
      w0.w = cvt_pk_bf16(xR[8 * o + 6].x, xR[8 * o + 7].x);
      w1.x = cvt_pk_bf16(xR[8 * o + 0].y, xR[8 * o + 1].y);
      w1.y = cvt_pk_bf16(xR[8 * o + 2].y, xR[8 * o + 3].y);
      w1.z = cvt_pk_bf16(xR[8 * o + 4].y, xR[8 * o + 5].y);
      w1.w = cvt_pk_bf16(xR[8 * o + 6].y, xR[8 * o + 7].y);
      const int kb = (32 * wave + 16 * o) ^ sx;
      *(uint4*)(Bb + kb)       = w0;   // row 2*lane
      *(uint4*)(Bb + 128 + kb) = w1;   // row 2*lane+1
    }
  };
  auto compute_kb2 = [&](const char* cb, int kb2, bool firstHalf) {
    short8 bfr[4];
#pragma unroll
    for (int ni = 0; ni < 4; ++ni)
      bfr[ni] = *(const short8*)(cb + boff[kb2] + ni * 2048);
    {  // gate r
      short8 a0 = *(const short8*)(cb + aoff[kb2]);
      short8 a1 = *(const short8*)(cb + aoff[kb2] + 2048);
#pragma unroll
      for (int ni = 0; ni < 4; ++ni) {
        acc_r[0][ni] = MFMA16(a0, bfr[ni], acc_r[0][ni]);
        acc_r[1][ni] = MFMA16(a1, bfr[ni], acc_r[1][ni]);
      }
    }
    {  // gate z
      short8 a0 = *(const short8*)(cb + aoff[kb2] + 8192);
      short8 a1 = *(const short8*)(cb + aoff[kb2] + 8192 + 2048);
#pragma unroll
      for (int ni = 0; ni < 4; ++ni) {
        acc_z[0][ni] = MFMA16(a0, bfr[ni], acc_z[0][ni]);
        acc_z[1][ni] = MFMA16(a1, bfr[ni], acc_z[1][ni]);
      }
    }
    {  // gate n -> acc_in (m-phase) / acc_hn (e-phase)
      short8 a0 = *(const short8*)(cb + aoff[kb2] + 16384);
      short8 a1 = *(const short8*)(cb + aoff[kb2] + 16384 + 2048);
      if (firstHalf) {
#pragma unroll
        for (int ni = 0; ni < 4; ++ni) {
          acc_in[0][ni] = MFMA16(a0, bfr[ni], acc_in[0][ni]);
          acc_in[1][ni] = MFMA16(a1, bfr[ni], acc_in[1][ni]);
        }
      } else {
#pragma unroll
        for (int ni = 0; ni < 4; ++ni) {
          acc_hn[0][ni] = MFMA16(a0, bfr[ni], acc_hn[0][ni]);
          acc_hn[1][ni] = MFMA16(a1, bfr[ni], acc_hn[1][ni]);
        }
      }
    }
  };

  // prologue: buf0 <- {A(0), X(0)}; X(1) loads issued (consumed at s=0 top)
  issue_A(0, smem);
  x_load(xm);                           // X(0)
  write_X(smem);                        // drains A(0)+X(0)
  x_load(xm + (size_t)(64 * NN));       // X(1)
  asm volatile("s_waitcnt lgkmcnt(0)" ::: "memory");
  __builtin_amdgcn_sched_barrier(0);
  __builtin_amdgcn_s_barrier();
  __builtin_amdgcn_sched_barrier(0);

#pragma unroll 1
  for (int s = 0; s < NSTEPS; ++s) {
    char* cb = smem + ((s & 1) ? BUF_BYTES : 0);
    char* nb = smem + ((s & 1) ? 0 : BUF_BYTES);
    const bool firstHalf = (s < 8);

    if (s + 1 < NSTEPS) {
      issue_A(s + 1, nb);               // 6 gloads, oldest vm ops of this step
      write_X(nb);                      // consume X(s+1) (step-old) -> vmcnt(6) wait
    }
    if (s + 2 < NSTEPS) {
      const int t = s + 2;
      x_load((t < 8 ? xm : xe) + (size_t)(t & 7) * (64 * NN));   // full-step flight
    }
    __builtin_amdgcn_sched_barrier(0);  // keep staging issued before compute

    __builtin_amdgcn_s_setprio(1);
    compute_kb2(cb, 0, firstHalf);
    compute_kb2(cb, 1, firstHalf);
    __builtin_amdgcn_s_setprio(0);

    if (s + 1 < NSTEPS) {
      if (s + 2 < NSTEPS)
        asm volatile("s_waitcnt vmcnt(16) lgkmcnt(0)" ::: "memory");  // A(s+1) done; X(s+2) flies
      else
        asm volatile("s_waitcnt vmcnt(0) lgkmcnt(0)" ::: "memory");   // s=14: drain A(15)
      __builtin_amdgcn_sched_barrier(0);
      __builtin_amdgcn_s_barrier();
      __builtin_amdgcn_sched_barrier(0);
    }
  }

  // epilogue: gates + blend (unchanged, verified R1-R13)
  const size_t obase = batch_off + (size_t)(ht * 64 + wm * 32) * NN + nt * BN + wn * 64;
  const float* ep = e_wv + obase;
  float* op = out + obase;
  const int rsub = (lane >> 4) << 2;
  const int csub = lane & 15;
#pragma unroll
  for (int mi = 0; mi < 2; ++mi)
#pragma unroll
    for (int ni = 0; ni < 4; ++ni) {
#pragma unroll
      for (int r = 0; r < 4; ++r) {
        size_t idx = (size_t)(mi * 16 + rsub + r) * NN + ni * 16 + csub;
        float pr  = acc_r[mi][ni][r];
        float pz  = acc_z[mi][ni][r];
        float vin = acc_in[mi][ni][r];
        float vhn = acc_hn[mi][ni][r];
        float rr  = 1.f / (1.f + __expf(-pr));
        float zz  = 1.f / (1.f + __expf(-pz));
        float ex  = __expf(2.f * (vin + rr * vhn));
        float nn2 = 1.f - 2.f / (ex + 1.f);      // tanh, inf-safe
        float ev  = ep[idx];
        op[idx] = (1.f - zz) * nn2 + zz * ev;
      }
    }
}

extern "C" void kernel_launch(void* const* d_in, const int* in_sizes, int n_in,
                              void* d_out, int out_size, void* d_ws, size_t ws_size,
                              hipStream_t stream) {
  const float* e_wv = (const float*)d_in[0];
  const float* m_wv = (const float*)d_in[1];
  const float* W_ih = (const float*)d_in[2];
  const float* W_hh = (const float*)d_in[3];
  float* out = (float*)d_out;
  __hip_bfloat16* wimg = (__hip_bfloat16*)d_ws;   // 3 MiB weight image

  (void)hipFuncSetAttribute((const void*)gru_main,
                            hipFuncAttributeMaxDynamicSharedMemorySize, LDS_TOTAL);

  prepack_w<<<(NBATCH * NSTEPS * 12288) / 256, 256, 0, stream>>>(W_ih, W_hh, wimg);
  gru_main<<<NBATCH * 8 * 64, THREADS, LDS_TOTAL, stream>>>(e_wv, m_wv, wimg, out);
}

// Round 16
// 315.637 us; speedup vs baseline: 1.0662x; 1.0608x over previous
//
#include <hip/hip_runtime.h>
#include <hip/hip_bf16.h>

// GRU-like fused cell: out = (1-z)*tanh(i_n + r*h_n) + z*e
// B=8, H=512, N=8192. bf16 MFMA 16x16x32, fp32 acc, fused epilogue.
//
// R15 -> R16: R15's phase-split RACED (mixed-type counted vmcnt: gload_lds DMA
// + reg-loads in one counted domain -- cross-type in-order retirement unproven;
// proven templates keep counted domains type-pure) and gained <=4% anyway.
// R16 = recovery to the empirical optimum R12 (317us bench, 0 conflicts),
// minus s_setprio (m190: negative on lockstep 2-phase GEMM; T5 needs
// phase-split to pay). Everything else identical to verified R12:
//   - 256 thr, BN=128, LDS 81920 -> 2 WGs/CU (independent barrier domains)
//   - coalesced X loads (wave owns 16 k-rows; per-row 64 lanes x float2)
//   - bank-floor B swizzle: stored byte = K ^ (((row>>1)&7)<<4), k-octet b128
//   - A via global_load_lds from pre-swizzled weight image (reg-staging spills)

#define HH 512
#define NBATCH 8
#define NN 8192
#define BN 128
#define BK 64
#define NSTEPS 16
#define THREADS 256
#define A_BYTES (192 * BK * 2)          // 24576
#define B_BYTES (BN * 128)              // 16384
#define BUF_BYTES (A_BYTES + B_BYTES)   // 40960
#define LDS_TOTAL (2 * BUF_BYTES)       // 81920 -> 2 WGs/CU

typedef __attribute__((ext_vector_type(8))) short short8;
typedef __attribute__((ext_vector_type(4))) float f32x4;

__device__ __forceinline__ unsigned cvt_pk_bf16(float a, float b) {
  unsigned r;
  asm("v_cvt_pk_bf16_f32 %0, %1, %2" : "=v"(r) : "v"(a), "v"(b));
  return r;
}

__device__ __forceinline__ void gload_lds16(const void* g, void* l) {
  __builtin_amdgcn_global_load_lds(
      (__attribute__((address_space(1))) void*)(g),
      (__attribute__((address_space(3))) void*)(l), 16, 0, 0);
}

#define MFMA16(a_, b_, c_) __builtin_amdgcn_mfma_f32_16x16x32_bf16((a_), (b_), (c_), 0, 0, 0)

// ---------------- weight pre-pack (unchanged, verified R1-R15) ----------------
__global__ void prepack_w(const float* __restrict__ W_ih, const float* __restrict__ W_hh,
                          __hip_bfloat16* __restrict__ ws) {
  int t = blockIdx.x * 256 + threadIdx.x;
  int blk = t / 12288;                              // ht*16 + s
  int e = t % 12288;
  int ra = e >> 6;                                  // 0..191
  int kk = (e & 63) ^ ((ra & 7) << 3);              // inverse of read-side XOR swizzle
  int gate = ra >> 6;
  int h = (blk >> 4) * 64 + (ra & 63);
  int row = gate * HH + h;
  int kg = (blk & 15) * 64 + kk;
  float v = (kg < 512) ? W_ih[row * 512 + kg] : W_hh[row * 512 + (kg - 512)];
  ws[t] = __float2bfloat16(v);
}

// ---------------- main fused kernel ----------------
__global__ __launch_bounds__(THREADS, 2)
void gru_main(const float* __restrict__ e_wv, const float* __restrict__ m_wv,
              const __hip_bfloat16* __restrict__ wimg, float* __restrict__ out) {
  extern __shared__ char smem[];
  const int tid  = threadIdx.x;
  const int lane = tid & 63;
  const int wave = tid >> 6;       // 0..3
  const int wm = wave >> 1;        // 0..1 : 32-row half of 64-h tile
  const int wn = wave & 1;         // 0..1 : 64-col half of 128-n tile

  // XCD swizzle (bijective: 4096 % 8 == 0), ht fastest.
  const int wg  = blockIdx.x;
  const int swz = (wg & 7) * 512 + (wg >> 3);
  const int ht  = swz & 7;
  const int nt  = (swz >> 3) & 63;
  const int b   = swz >> 9;

  const size_t batch_off = (size_t)b * HH * NN;
  // Coalesced X: wave w owns k-rows [16w,16w+16); per row 64 lanes x float2.
  const float* xm = m_wv + batch_off + (size_t)(16 * wave) * NN + nt * BN + 2 * lane;
  const float* xe = e_wv + batch_off + (size_t)(16 * wave) * NN + nt * BN + 2 * lane;
  const char*  wA = (const char*)wimg + (size_t)ht * NSTEPS * A_BYTES + tid * 16;

  f32x4 acc_r[2][4]  = {};
  f32x4 acc_z[2][4]  = {};
  f32x4 acc_in[2][4] = {};
  f32x4 acc_hn[2][4] = {};
  float2 xR[16];   // transient staged X (32 VGPRs)

  // Read offsets (R12-verified, 0 conflicts).
  int aoff[2], boff[2];
#pragma unroll
  for (int kb2 = 0; kb2 < 2; ++kb2) {
    const int K = kb2 * 64 + ((lane >> 4) << 4);
    aoff[kb2] = (wm * 32 + (lane & 15)) * 128 + (K ^ ((lane & 7) << 4));
    boff[kb2] = A_BYTES + (wn * 64 + (lane & 15)) * 128
              + (K ^ (((lane >> 1) & 7) << 4));
  }

  auto issue_A = [&](int s, char* nb) {
    const char* gA = wA + (size_t)s * A_BYTES;
    char* lA = nb + tid * 16;
#pragma unroll
    for (int i = 0; i < 6; ++i)
      gload_lds16(gA + i * 4096, lA + i * 4096);
  };
  auto x_load = [&](const float* xs) {
#pragma unroll
    for (int i = 0; i < 16; ++i)
      xR[i] = *(const float2*)(xs + (size_t)i * NN);
  };
  auto write_X = [&](char* nb) {
    // k-octet b128 writes: rows 2*lane, 2*lane+1; stored byte = K ^ ((lane&7)<<4)
    char* Bb = nb + A_BYTES + (2 * lane) * 128;
    const int sx = (lane & 7) << 4;
#pragma unroll
    for (int o = 0; o < 2; ++o) {
      uint4 w0, w1;
      w0.x = cvt_pk_bf16(xR[8 * o + 0].x, xR[8 * o + 1].x);
      w0.y = cvt_pk_bf16(xR[8 * o + 2].x, xR[8 * o + 3].x);
      w0.z = cvt_pk_bf16(xR[8 * o + 4].x, xR[8 * o + 5].x);
      w0.w = cvt_pk_bf16(xR[8 * o + 6].x, xR[8 * o + 7].x);
      w1.x = cvt_pk_bf16(xR[8 * o + 0].y, xR[8 * o + 1].y);
      w1.y = cvt_pk_bf16(xR[8 * o + 2].y, xR[8 * o + 3].y);
      w1.z = cvt_pk_bf16(xR[8 * o + 4].y, xR[8 * o + 5].y);
      w1.w = cvt_pk_bf16(xR[8 * o + 6].y, xR[8 * o + 7].y);
      const int kb = (32 * wave + 16 * o) ^ sx;
      *(uint4*)(Bb + kb)       = w0;   // row 2*lane
      *(uint4*)(Bb + 128 + kb) = w1;   // row 2*lane+1
    }
  };
  auto compute_kb2 = [&](const char* cb, int kb2, bool firstHalf) {
    short8 bfr[4];
#pragma unroll
    for (int ni = 0; ni < 4; ++ni)
      bfr[ni] = *(const short8*)(cb + boff[kb2] + ni * 2048);
    {  // gate r
      short8 a0 = *(const short8*)(cb + aoff[kb2]);
      short8 a1 = *(const short8*)(cb + aoff[kb2] + 2048);
#pragma unroll
      for (int ni = 0; ni < 4; ++ni) {
        acc_r[0][ni] = MFMA16(a0, bfr[ni], acc_r[0][ni]);
        acc_r[1][ni] = MFMA16(a1, bfr[ni], acc_r[1][ni]);
      }
    }
    {  // gate z
      short8 a0 = *(const short8*)(cb + aoff[kb2] + 8192);
      short8 a1 = *(const short8*)(cb + aoff[kb2] + 8192 + 2048);
#pragma unroll
      for (int ni = 0; ni < 4; ++ni) {
        acc_z[0][ni] = MFMA16(a0, bfr[ni], acc_z[0][ni]);
        acc_z[1][ni] = MFMA16(a1, bfr[ni], acc_z[1][ni]);
      }
    }
    {  // gate n -> acc_in (m-phase) / acc_hn (e-phase)
      short8 a0 = *(const short8*)(cb + aoff[kb2] + 16384);
      short8 a1 = *(const short8*)(cb + aoff[kb2] + 16384 + 2048);
      if (firstHalf) {
#pragma unroll
        for (int ni = 0; ni < 4; ++ni) {
          acc_in[0][ni] = MFMA16(a0, bfr[ni], acc_in[0][ni]);
          acc_in[1][ni] = MFMA16(a1, bfr[ni], acc_in[1][ni]);
        }
      } else {
#pragma unroll
        for (int ni = 0; ni < 4; ++ni) {
          acc_hn[0][ni] = MFMA16(a0, bfr[ni], acc_hn[0][ni]);
          acc_hn[1][ni] = MFMA16(a1, bfr[ni], acc_hn[1][ni]);
        }
      }
    }
  };

  // prologue: stage step 0 into buf0
  issue_A(0, smem);
  x_load(xm);
  write_X(smem);
  __syncthreads();

#pragma unroll 1
  for (int s = 0; s < NSTEPS; ++s) {
    char* cb = smem + ((s & 1) ? BUF_BYTES : 0);
    char* nb = smem + ((s & 1) ? 0 : BUF_BYTES);
    const bool pre = (s < NSTEPS - 1);
    const bool firstHalf = (s < 8);

    if (pre) {
      const int t = s + 1;
      x_load((t < 8 ? xm : xe) + (size_t)(t & 7) * (64 * NN));  // in flight over compute
      issue_A(t, nb);
    }
    compute_kb2(cb, 0, firstHalf);
    compute_kb2(cb, 1, firstHalf);
    if (pre) write_X(nb);
    __syncthreads();
  }

  // epilogue: gates + blend (unchanged, verified R1-R15)
  const size_t obase = batch_off + (size_t)(ht * 64 + wm * 32) * NN + nt * BN + wn * 64;
  const float* ep = e_wv + obase;
  float* op = out + obase;
  const int rsub = (lane >> 4) << 2;
  const int csub = lane & 15;
#pragma unroll
  for (int mi = 0; mi < 2; ++mi)
#pragma unroll
    for (int ni = 0; ni < 4; ++ni) {
#pragma unroll
      for (int r = 0; r < 4; ++r) {
        size_t idx = (size_t)(mi * 16 + rsub + r) * NN + ni * 16 + csub;
        float pr  = acc_r[mi][ni][r];
        float pz  = acc_z[mi][ni][r];
        float vin = acc_in[mi][ni][r];
        float vhn = acc_hn[mi][ni][r];
        float rr  = 1.f / (1.f + __expf(-pr));
        float zz  = 1.f / (1.f + __expf(-pz));
        float ex  = __expf(2.f * (vin + rr * vhn));
        float nn2 = 1.f - 2.f / (ex + 1.f);      // tanh, inf-safe
        float ev  = ep[idx];
        op[idx] = (1.f - zz) * nn2 + zz * ev;
      }
    }
}

extern "C" void kernel_launch(void* const* d_in, const int* in_sizes, int n_in,
                              void* d_out, int out_size, void* d_ws, size_t ws_size,
                              hipStream_t stream) {
  const float* e_wv = (const float*)d_in[0];
  const float* m_wv = (const float*)d_in[1];
  const float* W_ih = (const float*)d_in[2];
  const float* W_hh = (const float*)d_in[3];
  float* out = (float*)d_out;
  __hip_bfloat16* wimg = (__hip_bfloat16*)d_ws;   // 3 MiB weight image

  (void)hipFuncSetAttribute((const void*)gru_main,
                            hipFuncAttributeMaxDynamicSharedMemorySize, LDS_TOTAL);

  prepack_w<<<(NBATCH * NSTEPS * 12288) / 256, 256, 0, stream>>>(W_ih, W_hh, wimg);
  gru_main<<<NBATCH * 8 * 64, THREADS, LDS_TOTAL, stream>>>(e_wv, m_wv, wimg, out);
}

// Round 17
// 308.143 us; speedup vs baseline: 1.0921x; 1.0243x over previous
//
#include <hip/hip_runtime.h>
#include <hip/hip_bf16.h>

// GRU-like fused cell: out = (1-z)*tanh(i_n + r*h_n) + z*e
// B=8, H=512, N=8192. bf16 MFMA 16x16x32, fp32 acc, fused epilogue.
//
// R16 -> R17: R16 = the 2-phase structural ceiling (~650 TF-equiv). Escape =
// m201's type-pure all-DMA counted-vmcnt loop. Requirement: X must be bf16 +
// transposed + swizzled in memory -> prepack_x builds a 128MB image that is a
// byte-exact copy of what write_X used to put in LDS (read path UNCHANGED).
// Main loop then has ONLY global_load_lds (10/stage) + my counted vmcnt(10)
// (depth-2): no reg staging, no cvt, no compiler vm waits -> R15's
// mixed-domain race class is structurally gone. ws_size guard falls back to
// the verified R16 kernel.

#define HH 512
#define NBATCH 8
#define NN 8192
#define BN 128
#define BK 64
#define NSTEPS 16
#define THREADS 256
#define A_BYTES (192 * BK * 2)          // 24576
#define B_BYTES (BN * 128)              // 16384
#define BUF_BYTES (A_BYTES + B_BYTES)   // 40960
#define LDS_TOTAL (2 * BUF_BYTES)       // 81920 -> 2 WGs/CU

#define WIMG_BYTES (NBATCH * NSTEPS * 12288 * 2)          // 3,145,728
#define XIMG_BYTES ((size_t)NBATCH * NSTEPS * 64 * 16384) // 134,217,728
#define WS_NEED (WIMG_BYTES + XIMG_BYTES)

typedef __attribute__((ext_vector_type(8))) short short8;
typedef __attribute__((ext_vector_type(4))) float f32x4;

__device__ __forceinline__ unsigned cvt_pk_bf16(float a, float b) {
  unsigned r;
  asm("v_cvt_pk_bf16_f32 %0, %1, %2" : "=v"(r) : "v"(a), "v"(b));
  return r;
}

__device__ __forceinline__ void gload_lds16(const void* g, void* l) {
  __builtin_amdgcn_global_load_lds(
      (__attribute__((address_space(1))) void*)(g),
      (__attribute__((address_space(3))) void*)(l), 16, 0, 0);
}

#define MFMA16(a_, b_, c_) __builtin_amdgcn_mfma_f32_16x16x32_bf16((a_), (b_), (c_), 0, 0, 0)

#define BARRIER_FENCED() do {                               \
    __builtin_amdgcn_sched_barrier(0);                      \
    __builtin_amdgcn_s_barrier();                           \
    __builtin_amdgcn_sched_barrier(0);                      \
  } while (0)

// ---------------- weight pre-pack (unchanged, verified R1-R16) ----------------
__global__ void prepack_w(const float* __restrict__ W_ih, const float* __restrict__ W_hh,
                          __hip_bfloat16* __restrict__ ws) {
  int t = blockIdx.x * 256 + threadIdx.x;
  int blk = t / 12288;                              // ht*16 + s
  int e = t % 12288;
  int ra = e >> 6;                                  // 0..191
  int kk = (e & 63) ^ ((ra & 7) << 3);              // inverse of read-side XOR swizzle
  int gate = ra >> 6;
  int h = (blk >> 4) * 64 + (ra & 63);
  int row = gate * HH + h;
  int kg = (blk & 15) * 64 + kk;
  float v = (kg < 512) ? W_ih[row * 512 + kg] : W_hh[row * 512 + (kg - 512)];
  ws[t] = __float2bfloat16(v);
}

// ---------------- X pre-pack: f32 [k][n] -> bf16 image, byte-identical to the
// LDS B-tile write_X produced: stored_byte(n,k) = n*128 + ((2k) ^ ((n>>1&7)<<4))
// Block order: idx = (b*16 + s)*64 + nt; block = 16384 B.
__global__ void prepack_x(const float* __restrict__ e_wv, const float* __restrict__ m_wv,
                          char* __restrict__ ximg) {
  __shared__ __align__(16) char tile[16384];
  const int tid = threadIdx.x;
  const int idx = blockIdx.x;               // 0..8191
  const int b  = idx >> 10;
  const int s  = (idx >> 6) & 15;
  const int nt = idx & 63;
  const float* src = (s < 8 ? m_wv : e_wv)
                   + (size_t)b * HH * NN + (size_t)(64 * (s & 7)) * NN + nt * 128;
  // phase 1: coalesced f32x4 reads, scattered bf16 LDS writes (swizzled layout)
#pragma unroll
  for (int it = 0; it < 8; ++it) {
    int g = it * 256 + tid;                 // 0..2047 granules
    int k = g >> 5;                         // 0..63
    int n4 = (g & 31) << 2;                 // 0,4,..,124
    f32x4 v = *(const f32x4*)(src + (size_t)k * NN + n4);
#pragma unroll
    for (int j = 0; j < 4; ++j) {
      int n = n4 + j;
      int byteoff = n * 128 + ((2 * k) ^ (((n >> 1) & 7) << 4));
      *(__hip_bfloat16*)(tile + byteoff) = __float2bfloat16(v[j]);
    }
  }
  __syncthreads();
  // phase 2: linear b128 LDS reads -> coalesced global writes
  char* dst = ximg + (size_t)idx * 16384;
#pragma unroll
  for (int it = 0; it < 4; ++it) {
    int p = it * 4096 + tid * 16;
    *(uint4*)(dst + p) = *(const uint4*)(tile + p);
  }
}

// ---------------- main fused kernel, all-DMA staging (m201 pattern) ----------------
__global__ __launch_bounds__(THREADS, 2)
void gru_main_dma(const float* __restrict__ e_wv,
                  const __hip_bfloat16* __restrict__ wimg,
                  const char* __restrict__ ximg, float* __restrict__ out) {
  extern __shared__ char smem[];
  const int tid  = threadIdx.x;
  const int lane = tid & 63;
  const int wave = tid >> 6;       // 0..3
  const int wm = wave >> 1;        // 0..1 : 32-row half of 64-h tile
  const int wn = wave & 1;         // 0..1 : 64-col half of 128-n tile

  // XCD swizzle (bijective: 4096 % 8 == 0), ht fastest.
  const int wg  = blockIdx.x;
  const int swz = (wg & 7) * 512 + (wg >> 3);
  const int ht  = swz & 7;
  const int nt  = (swz >> 3) & 63;
  const int b   = swz >> 9;

  const size_t batch_off = (size_t)b * HH * NN;
  const char* wA  = (const char*)wimg + (size_t)ht * NSTEPS * A_BYTES + tid * 16;
  const char* xib = ximg + ((size_t)(b * 16) * 64 + nt) * 16384 + tid * 16;

  f32x4 acc_r[2][4]  = {};
  f32x4 acc_z[2][4]  = {};
  f32x4 acc_in[2][4] = {};
  f32x4 acc_hn[2][4] = {};

  // Read offsets (R12/R16-verified, 0 conflicts; image matches write_X bytes).
  int aoff[2], boff[2];
#pragma unroll
  for (int kb2 = 0; kb2 < 2; ++kb2) {
    const int K = kb2 * 64 + ((lane >> 4) << 4);
    aoff[kb2] = (wm * 32 + (lane & 15)) * 128 + (K ^ ((lane & 7) << 4));
    boff[kb2] = A_BYTES + (wn * 64 + (lane & 15)) * 128
              + (K ^ (((lane >> 1) & 7) << 4));
  }

  auto stage = [&](int t, char* buf) {   // 10 gload_lds, type-pure vm domain
    const char* gA = wA + (size_t)t * A_BYTES;
    char* lA = buf + tid * 16;
#pragma unroll
    for (int i = 0; i < 6; ++i)
      gload_lds16(gA + i * 4096, lA + i * 4096);
    const char* gB = xib + (size_t)t * (64 * 16384);
    char* lB = buf + A_BYTES + tid * 16;
#pragma unroll
    for (int i = 0; i < 4; ++i)
      gload_lds16(gB + i * 4096, lB + i * 4096);
  };
  auto compute_kb2 = [&](const char* cb, int kb2, bool firstHalf) {
    short8 bfr[4];
#pragma unroll
    for (int ni = 0; ni < 4; ++ni)
      bfr[ni] = *(const short8*)(cb + boff[kb2] + ni * 2048);
    {  // gate r
      short8 a0 = *(const short8*)(cb + aoff[kb2]);
      short8 a1 = *(const short8*)(cb + aoff[kb2] + 2048);
#pragma unroll
      for (int ni = 0; ni < 4; ++ni) {
        acc_r[0][ni] = MFMA16(a0, bfr[ni], acc_r[0][ni]);
        acc_r[1][ni] = MFMA16(a1, bfr[ni], acc_r[1][ni]);
      }
    }
    {  // gate z
      short8 a0 = *(const short8*)(cb + aoff[kb2] + 8192);
      short8 a1 = *(const short8*)(cb + aoff[kb2] + 8192 + 2048);
#pragma unroll
      for (int ni = 0; ni < 4; ++ni) {
        acc_z[0][ni] = MFMA16(a0, bfr[ni], acc_z[0][ni]);
        acc_z[1][ni] = MFMA16(a1, bfr[ni], acc_z[1][ni]);
      }
    }
    {  // gate n -> acc_in (m-phase) / acc_hn (e-phase)
      short8 a0 = *(const short8*)(cb + aoff[kb2] + 16384);
      short8 a1 = *(const short8*)(cb + aoff[kb2] + 16384 + 2048);
      if (firstHalf) {
#pragma unroll
        for (int ni = 0; ni < 4; ++ni) {
          acc_in[0][ni] = MFMA16(a0, bfr[ni], acc_in[0][ni]);
          acc_in[1][ni] = MFMA16(a1, bfr[ni], acc_in[1][ni]);
        }
      } else {
#pragma unroll
        for (int ni = 0; ni < 4; ++ni) {
          acc_hn[0][ni] = MFMA16(a0, bfr[ni], acc_hn[0][ni]);
          acc_hn[1][ni] = MFMA16(a1, bfr[ni], acc_hn[1][ni]);
        }
      }
    }
  };

  // prologue: stage t0 -> buf0, t1 -> buf1; wait own t0 batch; barrier.
  stage(0, smem);
  stage(1, smem + BUF_BYTES);
  asm volatile("s_waitcnt vmcnt(10)" ::: "memory");   // t0 landed; t1 in flight
  BARRIER_FENCED();

#pragma unroll 1
  for (int t = 0; t < NSTEPS; ++t) {
    char* cb = smem + ((t & 1) ? BUF_BYTES : 0);
    const bool firstHalf = (t < 8);

    compute_kb2(cb, 0, firstHalf);
    compute_kb2(cb, 1, firstHalf);

    // barrier A: all waves done READING cb (ds_reads consumed via lgkm before MFMA)
    asm volatile("s_waitcnt lgkmcnt(0)" ::: "memory");
    BARRIER_FENCED();

    if (t + 2 < NSTEPS) stage(t + 2, cb);   // refill the just-freed buffer

    if (t + 1 < NSTEPS) {
      // barrier B: everyone's t+1 batch landed; t+2 stays in flight.
      if (t + 2 < NSTEPS)
        asm volatile("s_waitcnt vmcnt(10)" ::: "memory");
      else
        asm volatile("s_waitcnt vmcnt(0)" ::: "memory");
      BARRIER_FENCED();
    }
  }

  // epilogue: gates + blend (unchanged, verified R1-R16)
  const size_t obase = batch_off + (size_t)(ht * 64 + wm * 32) * NN + nt * BN + wn * 64;
  const float* ep = e_wv + obase;
  float* op = out + obase;
  const int rsub = (lane >> 4) << 2;
  const int csub = lane & 15;
#pragma unroll
  for (int mi = 0; mi < 2; ++mi)
#pragma unroll
    for (int ni = 0; ni < 4; ++ni) {
#pragma unroll
      for (int r = 0; r < 4; ++r) {
        size_t idx = (size_t)(mi * 16 + rsub + r) * NN + ni * 16 + csub;
        float pr  = acc_r[mi][ni][r];
        float pz  = acc_z[mi][ni][r];
        float vin = acc_in[mi][ni][r];
        float vhn = acc_hn[mi][ni][r];
        float rr  = 1.f / (1.f + __expf(-pr));
        float zz  = 1.f / (1.f + __expf(-pz));
        float ex  = __expf(2.f * (vin + rr * vhn));
        float nn2 = 1.f - 2.f / (ex + 1.f);      // tanh, inf-safe
        float ev  = ep[idx];
        op[idx] = (1.f - zz) * nn2 + zz * ev;
      }
    }
}

// ---------------- fallback: R16 verbatim (used when ws is too small) ----------------
__global__ __launch_bounds__(THREADS, 2)
void gru_main_fb(const float* __restrict__ e_wv, const float* __restrict__ m_wv,
                 const __hip_bfloat16* __restrict__ wimg, float* __restrict__ out) {
  extern __shared__ char smem[];
  const int tid  = threadIdx.x;
  const int lane = tid & 63;
  const int wave = tid >> 6;
  const int wm = wave >> 1;
  const int wn = wave & 1;
  const int wg  = blockIdx.x;
  const int swz = (wg & 7) * 512 + (wg >> 3);
  const int ht  = swz & 7;
  const int nt  = (swz >> 3) & 63;
  const int b   = swz >> 9;
  const size_t batch_off = (size_t)b * HH * NN;
  const float* xm = m_wv + batch_off + (size_t)(16 * wave) * NN + nt * BN + 2 * lane;
  const float* xe = e_wv + batch_off + (size_t)(16 * wave) * NN + nt * BN + 2 * lane;
  const char*  wA = (const char*)wimg + (size_t)ht * NSTEPS * A_BYTES + tid * 16;
  f32x4 acc_r[2][4]  = {};
  f32x4 acc_z[2][4]  = {};
  f32x4 acc_in[2][4] = {};
  f32x4 acc_hn[2][4] = {};
  float2 xR[16];
  int aoff[2], boff[2];
#pragma unroll
  for (int kb2 = 0; kb2 < 2; ++kb2) {
    const int K = kb2 * 64 + ((lane >> 4) << 4);
    aoff[kb2] = (wm * 32 + (lane & 15)) * 128 + (K ^ ((lane & 7) << 4));
    boff[kb2] = A_BYTES + (wn * 64 + (lane & 15)) * 128 + (K ^ (((lane >> 1) & 7) << 4));
  }
  auto issue_A = [&](int s, char* nb) {
    const char* gA = wA + (size_t)s * A_BYTES;
    char* lA = nb + tid * 16;
#pragma unroll
    for (int i = 0; i < 6; ++i) gload_lds16(gA + i * 4096, lA + i * 4096);
  };
  auto x_load = [&](const float* xs) {
#pragma unroll
    for (int i = 0; i < 16; ++i) xR[i] = *(const float2*)(xs + (size_t)i * NN);
  };
  auto write_X = [&](char* nb) {
    char* Bb = nb + A_BYTES + (2 * lane) * 128;
    const int sx = (lane & 7) << 4;
#pragma unroll
    for (int o = 0; o < 2; ++o) {
      uint4 w0, w1;
      w0.x = cvt_pk_bf16(xR[8 * o + 0].x, xR[8 * o + 1].x);
      w0.y = cvt_pk_bf16(xR[8 * o + 2].x, xR[8 * o + 3].x);
      w0.z = cvt_pk_bf16(xR[8 * o + 4].x, xR[8 * o + 5].x);
      w0.w = cvt_pk_bf16(xR[8 * o + 6].x, xR[8 * o + 7].x);
      w1.x = cvt_pk_bf16(xR[8 * o + 0].y, xR[8 * o + 1].y);
      w1.y = cvt_pk_bf16(xR[8 * o + 2].y, xR[8 * o + 3].y);
      w1.z = cvt_pk_bf16(xR[8 * o + 4].y, xR[8 * o + 5].y);
      w1.w = cvt_pk_bf16(xR[8 * o + 6].y, xR[8 * o + 7].y);
      const int kb = (32 * wave + 16 * o) ^ sx;
      *(uint4*)(Bb + kb)       = w0;
      *(uint4*)(Bb + 128 + kb) = w1;
    }
  };
  auto compute_kb2 = [&](const char* cb, int kb2, bool firstHalf) {
    short8 bfr[4];
#pragma unroll
    for (int ni = 0; ni < 4; ++ni) bfr[ni] = *(const short8*)(cb + boff[kb2] + ni * 2048);
    {
      short8 a0 = *(const short8*)(cb + aoff[kb2]);
      short8 a1 = *(const short8*)(cb + aoff[kb2] + 2048);
#pragma unroll
      for (int ni = 0; ni < 4; ++ni) {
        acc_r[0][ni] = MFMA16(a0, bfr[ni], acc_r[0][ni]);
        acc_r[1][ni] = MFMA16(a1, bfr[ni], acc_r[1][ni]);
      }
    }
    {
      short8 a0 = *(const short8*)(cb + aoff[kb2] + 8192);
      short8 a1 = *(const short8*)(cb + aoff[kb2] + 8192 + 2048);
#pragma unroll
      for (int ni = 0; ni < 4; ++ni) {
        acc_z[0][ni] = MFMA16(a0, bfr[ni], acc_z[0][ni]);
        acc_z[1][ni] = MFMA16(a1, bfr[ni], acc_z[1][ni]);
      }
    }
    {
      short8 a0 = *(const short8*)(cb + aoff[kb2] + 16384);
      short8 a1 = *(const short8*)(cb + aoff[kb2] + 16384 + 2048);
      if (firstHalf) {
#pragma unroll
        for (int ni = 0; ni < 4; ++ni) {
          acc_in[0][ni] = MFMA16(a0, bfr[ni], acc_in[0][ni]);
          acc_in[1][ni] = MFMA16(a1, bfr[ni], acc_in[1][ni]);
        }
      } else {
#pragma unroll
        for (int ni = 0; ni < 4; ++ni) {
          acc_hn[0][ni] = MFMA16(a0, bfr[ni], acc_hn[0][ni]);
          acc_hn[1][ni] = MFMA16(a1, bfr[ni], acc_hn[1][ni]);
        }
      }
    }
  };
  issue_A(0, smem);
  x_load(xm);
  write_X(smem);
  __syncthreads();
#pragma unroll 1
  for (int s = 0; s < NSTEPS; ++s) {
    char* cb = smem + ((s & 1) ? BUF_BYTES : 0);
    char* nb = smem + ((s & 1) ? 0 : BUF_BYTES);
    const bool pre = (s < NSTEPS - 1);
    const bool firstHalf = (s < 8);
    if (pre) {
      const int t = s + 1;
      x_load((t < 8 ? xm : xe) + (size_t)(t & 7) * (64 * NN));
      issue_A(t, nb);
    }
    compute_kb2(cb, 0, firstHalf);
    compute_kb2(cb, 1, firstHalf);
    if (pre) write_X(nb);
    __syncthreads();
  }
  const size_t obase = batch_off + (size_t)(ht * 64 + wm * 32) * NN + nt * BN + wn * 64;
  const float* ep = e_wv + obase;
  float* op = out + obase;
  const int rsub = (lane >> 4) << 2;
  const int csub = lane & 15;
#pragma unroll
  for (int mi = 0; mi < 2; ++mi)
#pragma unroll
    for (int ni = 0; ni < 4; ++ni) {
#pragma unroll
      for (int r = 0; r < 4; ++r) {
        size_t idx = (size_t)(mi * 16 + rsub + r) * NN + ni * 16 + csub;
        float pr  = acc_r[mi][ni][r];
        float pz  = acc_z[mi][ni][r];
        float vin = acc_in[mi][ni][r];
        float vhn = acc_hn[mi][ni][r];
        float rr  = 1.f / (1.f + __expf(-pr));
        float zz  = 1.f / (1.f + __expf(-pz));
        float ex  = __expf(2.f * (vin + rr * vhn));
        float nn2 = 1.f - 2.f / (ex + 1.f);
        float ev  = ep[idx];
        op[idx] = (1.f - zz) * nn2 + zz * ev;
      }
    }
}

extern "C" void kernel_launch(void* const* d_in, const int* in_sizes, int n_in,
                              void* d_out, int out_size, void* d_ws, size_t ws_size,
                              hipStream_t stream) {
  const float* e_wv = (const float*)d_in[0];
  const float* m_wv = (const float*)d_in[1];
  const float* W_ih = (const float*)d_in[2];
  const float* W_hh = (const float*)d_in[3];
  float* out = (float*)d_out;
  __hip_bfloat16* wimg = (__hip_bfloat16*)d_ws;
  char* ximg = (char*)d_ws + WIMG_BYTES;

  (void)hipFuncSetAttribute((const void*)gru_main_dma,
                            hipFuncAttributeMaxDynamicSharedMemorySize, LDS_TOTAL);
  (void)hipFuncSetAttribute((const void*)gru_main_fb,
                            hipFuncAttributeMaxDynamicSharedMemorySize, LDS_TOTAL);

  prepack_w<<<(NBATCH * NSTEPS * 12288) / 256, 256, 0, stream>>>(W_ih, W_hh, wimg);

  if (ws_size >= WS_NEED) {
    prepack_x<<<NBATCH * NSTEPS * 64, 256, 0, stream>>>(e_wv, m_wv, ximg);
    gru_main_dma<<<NBATCH * 8 * 64, THREADS, LDS_TOTAL, stream>>>(e_wv, wimg, ximg, out);
  } else {
    gru_main_fb<<<NBATCH * 8 * 64, THREADS, LDS_TOTAL, stream>>>(e_wv, m_wv, wimg, out);
  }
}